// Round 4
// baseline (1066.708 us; speedup 1.0000x reference)
//
#include <hip/hip_runtime.h>
#include <cstddef>
#include <cstdint>

// Shapes fixed by reference setup_inputs():
#define T_LEN 2048
#define B_SZ  32
#define D_SZ  512
#define BD    (B_SZ * D_SZ)   // 16384

// ---------------------------------------------------------------------------
// GEMM replicating a single-accumulator fp32 sgemm bit-exactly:
//   per output element: acc = sequential fmaf chain over k=0..511 (ascending)
//                       c   = acc + bias[e]
// Covers oneDNN brgemm / XNNPACK f32 gemm / Eigen kc>=512 / naive FMA loop:
// all use one accumulator per C element over the full K, fused FMA, k ascending.
// ---------------------------------------------------------------------------
#define BM  64
#define BN  64
#define LDP 20    // padded LDS row stride (floats); 80 B rows stay 16B-aligned

__global__ __launch_bounds__(256) void gemm_chain32_kernel(
    const float* __restrict__ A,     // [rows, 512]
    const float* __restrict__ W,     // [512, 512]
    const float* __restrict__ bias,  // [512]
    float* __restrict__ Y)           // [rows, 512]
{
#pragma clang fp contract(off)
  __shared__ float As[BM][LDP];
  __shared__ float Bs[BN][LDP];

  const int tid = threadIdx.x;
  const int tx  = tid & 15;           // n-dir (4 cols each)
  const int ty  = tid >> 4;           // m-dir (4 rows each)
  const int m0  = blockIdx.x * BM;
  const int n0  = blockIdx.y * BN;
  const int lr  = tid >> 2;           // staging row 0..63
  const int lq  = tid & 3;            // staging quad 0..3
  // B rows stored with quad slot rotated by (row>>2); compile-time for readers.
  const int wslot = (((lq + (lr >> 2)) & 3) << 2);

  float acc[4][4];
#pragma unroll
  for (int i = 0; i < 4; ++i)
#pragma unroll
    for (int j = 0; j < 4; ++j) acc[i][j] = 0.0f;

  const float* Ap = A + (size_t)(m0 + lr) * D_SZ + (lq << 2);
  const float* Wp = W + (size_t)(n0 + lr) * D_SZ + (lq << 2);

#pragma unroll 1
  for (int c = 0; c < 32; ++c) {      // 32 chunks of 16 = k ascending 0..511
    const int k0 = c << 4;
    __syncthreads();
    *(float4*)&As[lr][lq << 2] = *(const float4*)(Ap + k0);
    *(float4*)&Bs[lr][wslot]   = *(const float4*)(Wp + k0);
    __syncthreads();

    float a[4][16];
#pragma unroll
    for (int i = 0; i < 4; ++i)
#pragma unroll
      for (int q = 0; q < 4; ++q)
        *(float4*)&a[i][q << 2] = *(const float4*)&As[(ty << 2) + i][q << 2];

#pragma unroll
    for (int j = 0; j < 4; ++j) {
      float bf[16];
#pragma unroll
      for (int q = 0; q < 4; ++q)
        *(float4*)&bf[q << 2] =
            *(const float4*)&Bs[(tx << 2) + j][((q + tx) & 3) << 2];
#pragma unroll
      for (int i = 0; i < 4; ++i)
#pragma unroll
        for (int e = 0; e < 16; ++e)      // ascending k within chunk
          acc[i][j] = fmaf(a[i][e], bf[e], acc[i][j]);
    }
  }

  // c = acc + bias (bias is zeros; add kept for faithful final rounding)
#pragma unroll
  for (int i = 0; i < 4; ++i) {
    float* yp = Y + (size_t)(m0 + (ty << 2) + i) * D_SZ + n0 + (tx << 2);
    float4 r;
    r.x = acc[i][0] + bias[n0 + (tx << 2) + 0];
    r.y = acc[i][1] + bias[n0 + (tx << 2) + 1];
    r.z = acc[i][2] + bias[n0 + (tx << 2) + 2];
    r.w = acc[i][3] + bias[n0 + (tx << 2) + 3];
    *(float4*)yp = r;
  }
}

// ---------------------------------------------------------------------------
// LIF scans, fp32, exact reference op order:
//   v = v + (c - v)*0.5f  (== /2.0 bitwise);  s = (v - 1.0f) >= 0;  v = s?0:v
// ---------------------------------------------------------------------------
__global__ __launch_bounds__(64) void lif_fwd_kernel(
    const float* __restrict__ Y, float* __restrict__ out,
    int tlen, float* __restrict__ vstate, int carry)
{
#pragma clang fp contract(off)
  const int idx = blockIdx.x * 64 + threadIdx.x;
  float v = carry ? vstate[idx] : 0.0f;
  const float* p = Y + idx;
  float* o = out + idx;
#pragma unroll 16
  for (int t = 0; t < tlen; ++t) {
    const float c = p[(size_t)t * BD];
    v = v + (c - v) * 0.5f;
    const bool s = (v - 1.0f) >= 0.0f;
    o[(size_t)t * BD] = s ? 1.0f : 0.0f;
    v = s ? 0.0f : v;
  }
  vstate[idx] = v;
}

__global__ __launch_bounds__(64) void lif_bwd_kernel(
    const float* __restrict__ Y, float* __restrict__ out,
    int tlen, float* __restrict__ vstate, int carry)
{
#pragma clang fp contract(off)
  const int idx = blockIdx.x * 64 + threadIdx.x;
  float v = carry ? vstate[idx] : 0.0f;
#pragma unroll 16
  for (int tt = 0; tt < tlen; ++tt) {
    const size_t t = (size_t)(tlen - 1 - tt);
    const float c = Y[t * BD + idx];
    v = v + (c - v) * 0.5f;
    const bool s = (v - 1.0f) >= 0.0f;
    out[t * BD + idx] += s ? 1.0f : 0.0f;   // {0,1}+{0,1}: exact in fp32
    v = s ? 0.0f : v;
  }
  vstate[idx] = v;
}

// ---------------------------------------------------------------------------
extern "C" void kernel_launch(void* const* d_in, const int* in_sizes, int n_in,
                              void* d_out, int out_size, void* d_ws, size_t ws_size,
                              hipStream_t stream)
{
  const float* x = (const float*)d_in[0];   // [T, B, D]
  const float* W = (const float*)d_in[1];   // [D, D]
  const float* b = (const float*)d_in[2];   // [D]
  float* out = (float*)d_out;               // [T, B, D]

  const size_t vbytes     = (size_t)BD * sizeof(float);
  const size_t full_bytes = (size_t)T_LEN * BD * sizeof(float);   // 134 MB

  if (ws_size >= full_bytes + vbytes) {
    float* Y      = (float*)d_ws;
    float* vstate = (float*)((char*)d_ws + full_bytes);
    dim3 grid(T_LEN * B_SZ / BM, D_SZ / BN);
    gemm_chain32_kernel<<<grid, 256, 0, stream>>>(x, W, b, Y);
    lif_fwd_kernel<<<BD / 64, 64, 0, stream>>>(Y, out, T_LEN, vstate, 0);
    lif_bwd_kernel<<<BD / 64, 64, 0, stream>>>(Y, out, T_LEN, vstate, 0);
  } else {
    // Chunked fallback: GEMM per chunk in each direction, v carried.
    const size_t avail = ws_size > vbytes ? ws_size - vbytes : 0;
    int Tc = (int)(avail / ((size_t)BD * sizeof(float)));
    Tc &= ~1;
    if (Tc < 2) Tc = 2;
    if (Tc > T_LEN) Tc = T_LEN;
    float* Y      = (float*)d_ws;
    float* vstate = (float*)((char*)d_ws + (size_t)Tc * BD * sizeof(float));

    int first = 1;
    for (int t0 = 0; t0 < T_LEN; t0 += Tc) {
      const int len = (Tc < T_LEN - t0) ? Tc : (T_LEN - t0);
      dim3 grid(len * B_SZ / BM, D_SZ / BN);
      gemm_chain32_kernel<<<grid, 256, 0, stream>>>(x + (size_t)t0 * BD, W, b, Y);
      lif_fwd_kernel<<<BD / 64, 64, 0, stream>>>(Y, out + (size_t)t0 * BD, len,
                                                 vstate, first ? 0 : 1);
      first = 0;
    }
    first = 1;
    int t0 = ((T_LEN - 1) / Tc) * Tc;
    for (; t0 >= 0; t0 -= Tc) {
      const int len = (Tc < T_LEN - t0) ? Tc : (T_LEN - t0);
      dim3 grid(len * B_SZ / BM, D_SZ / BN);
      gemm_chain32_kernel<<<grid, 256, 0, stream>>>(x + (size_t)t0 * BD, W, b, Y);
      lif_bwd_kernel<<<BD / 64, 64, 0, stream>>>(Y, out + (size_t)t0 * BD, len,
                                                 vstate, first ? 0 : 1);
      first = 0;
    }
  }
}

// Round 5
// 712.653 us; speedup vs baseline: 1.4968x; 1.4968x over previous
//
#include <hip/hip_runtime.h>
#include <cstddef>
#include <cstdint>

// Shapes fixed by reference setup_inputs():
#define T_LEN 2048
#define B_SZ  32
#define D_SZ  512
#define BD    (B_SZ * D_SZ)   // 16384

// ---------------------------------------------------------------------------
// GEMM: per output element, single sequential fmaf chain over k=0..511
// ascending, then + bias[e]. (Verified bit-exact vs harness ref in R4.)
// 128x128 block tile, 8x8 per-thread microtile, interleaved lane mapping
// (m = ty + 16*i, n = tx + 16*j) so LDS reads are <=2-way bank conflicts.
// ---------------------------------------------------------------------------
#define BM  128
#define BN  128
#define LDP 20    // padded LDS row stride in floats (80 B, 16B-aligned)

__global__ __launch_bounds__(256) void gemm8x8_kernel(
    const float* __restrict__ A,     // [rows, 512]
    const float* __restrict__ W,     // [512, 512]
    const float* __restrict__ bias,  // [512]
    float* __restrict__ Y)           // [rows, 512]
{
#pragma clang fp contract(off)
  __shared__ float As[BM][LDP];
  __shared__ float Bs[BN][LDP];

  const int tid = threadIdx.x;
  const int tx  = tid & 15;          // n-lane: n = tx + 16*j
  const int ty  = tid >> 4;          // m-lane: m = ty + 16*i
  const int m0  = blockIdx.x * BM;
  const int n0  = blockIdx.y * BN;

  // staging: thread loads 2 float4 of A-tile and 2 of B-tile per chunk
  const int sr = tid >> 2;           // 0..63 tile row
  const int sq = (tid & 3) << 2;     // k-quad offset in floats

  const float* Ap0 = A + (size_t)(m0 + sr)      * D_SZ + sq;
  const float* Ap1 = A + (size_t)(m0 + 64 + sr) * D_SZ + sq;
  const float* Wp0 = W + (size_t)(n0 + sr)      * D_SZ + sq;
  const float* Wp1 = W + (size_t)(n0 + 64 + sr) * D_SZ + sq;

  float acc[8][8];
#pragma unroll
  for (int i = 0; i < 8; ++i)
#pragma unroll
    for (int j = 0; j < 8; ++j) acc[i][j] = 0.0f;

  float4 pa0 = *(const float4*)(Ap0);
  float4 pa1 = *(const float4*)(Ap1);
  float4 pb0 = *(const float4*)(Wp0);
  float4 pb1 = *(const float4*)(Wp1);

#pragma unroll 1
  for (int k0 = 0; k0 < D_SZ; k0 += 16) {
    __syncthreads();
    *(float4*)&As[sr][sq]      = pa0;
    *(float4*)&As[64 + sr][sq] = pa1;
    *(float4*)&Bs[sr][sq]      = pb0;
    *(float4*)&Bs[64 + sr][sq] = pb1;
    __syncthreads();

    if (k0 + 16 < D_SZ) {            // prefetch next chunk; overlaps compute
      pa0 = *(const float4*)(Ap0 + k0 + 16);
      pa1 = *(const float4*)(Ap1 + k0 + 16);
      pb0 = *(const float4*)(Wp0 + k0 + 16);
      pb1 = *(const float4*)(Wp1 + k0 + 16);
    }

#pragma unroll
    for (int kq = 0; kq < 4; ++kq) {
      float4 b[8];
#pragma unroll
      for (int j = 0; j < 8; ++j)
        b[j] = *(const float4*)&Bs[tx + 16 * j][kq << 2];
#pragma unroll
      for (int i = 0; i < 8; ++i) {
        const float4 a = *(const float4*)&As[ty + 16 * i][kq << 2];
#pragma unroll
        for (int j = 0; j < 8; ++j) {
          // per-element chain: k ascending (x,y,z,w), kq ascending, k0 ascending
          acc[i][j] = fmaf(a.x, b[j].x, acc[i][j]);
          acc[i][j] = fmaf(a.y, b[j].y, acc[i][j]);
          acc[i][j] = fmaf(a.z, b[j].z, acc[i][j]);
          acc[i][j] = fmaf(a.w, b[j].w, acc[i][j]);
        }
      }
    }
  }

#pragma unroll
  for (int i = 0; i < 8; ++i) {
    const int m = m0 + ty + 16 * i;
#pragma unroll
    for (int j = 0; j < 8; ++j) {
      const int n = n0 + tx + 16 * j;
      Y[(size_t)m * D_SZ + n] = acc[i][j] + bias[n];
    }
  }
}

// ---------------------------------------------------------------------------
// Scan phase 1: fwd and bwd LIF scans run concurrently (one kernel), spike
// bits packed 32-per-word into side buffers (no out read-modify-write).
//   v = v + (c - v)*0.5f;  s = (v - 1.0f) >= 0;  v = s ? 0 : v
// ---------------------------------------------------------------------------
__global__ __launch_bounds__(64) void scan_dirs_kernel(
    const float* __restrict__ Y,
    uint32_t* __restrict__ bits_f,
    uint32_t* __restrict__ bits_b)
{
#pragma clang fp contract(off)
  const int blk = blockIdx.x;
  const bool fwd = blk < 256;
  const int idx = ((fwd ? blk : blk - 256) << 6) + threadIdx.x;
  float v = 0.0f;

  if (fwd) {
#pragma unroll 1
    for (int g = 0; g < 64; ++g) {
      float c[32];
#pragma unroll
      for (int j = 0; j < 32; ++j)
        c[j] = Y[(size_t)(g * 32 + j) * BD + idx];
      uint32_t w = 0;
#pragma unroll
      for (int j = 0; j < 32; ++j) {
        v = v + (c[j] - v) * 0.5f;
        const bool s = (v - 1.0f) >= 0.0f;
        w |= (uint32_t)s << j;
        v = s ? 0.0f : v;
      }
      bits_f[g * BD + idx] = w;
    }
  } else {
#pragma unroll 1
    for (int g = 63; g >= 0; --g) {
      float c[32];
#pragma unroll
      for (int j = 0; j < 32; ++j)
        c[j] = Y[(size_t)(g * 32 + j) * BD + idx];
      uint32_t w = 0;
#pragma unroll
      for (int j = 31; j >= 0; --j) {   // t descending overall
        v = v + (c[j] - v) * 0.5f;
        const bool s = (v - 1.0f) >= 0.0f;
        w |= (uint32_t)s << j;
        v = s ? 0.0f : v;
      }
      bits_b[g * BD + idx] = w;
    }
  }
}

// Scan phase 2: out[t,idx] = fwd_bit + bwd_bit, float4-vectorized write.
__global__ __launch_bounds__(256) void combine_kernel(
    const uint32_t* __restrict__ bf,
    const uint32_t* __restrict__ bb,
    float* __restrict__ out)
{
  const int gid = blockIdx.x * 256 + threadIdx.x;
  const int f0  = gid << 2;            // first of 4 consecutive out elements
  const int t   = f0 / BD;
  const int i0  = f0 & (BD - 1);
  const int g   = t >> 5;
  const int bit = t & 31;
  const uint4 wf = *(const uint4*)(bf + g * BD + i0);
  const uint4 wb = *(const uint4*)(bb + g * BD + i0);
  float4 r;
  r.x = (float)(((wf.x >> bit) & 1u) + ((wb.x >> bit) & 1u));
  r.y = (float)(((wf.y >> bit) & 1u) + ((wb.y >> bit) & 1u));
  r.z = (float)(((wf.z >> bit) & 1u) + ((wb.z >> bit) & 1u));
  r.w = (float)(((wf.w >> bit) & 1u) + ((wb.w >> bit) & 1u));
  *(float4*)(out + (size_t)f0) = r;
}

// ---------------------------------------------------------------------------
// Fallback scans (used only if ws is too small for the bit buffers).
// ---------------------------------------------------------------------------
__global__ __launch_bounds__(64) void lif_fwd_kernel(
    const float* __restrict__ Y, float* __restrict__ out,
    int tlen, float* __restrict__ vstate, int carry)
{
#pragma clang fp contract(off)
  const int idx = blockIdx.x * 64 + threadIdx.x;
  float v = carry ? vstate[idx] : 0.0f;
#pragma unroll 16
  for (int t = 0; t < tlen; ++t) {
    const float c = Y[(size_t)t * BD + idx];
    v = v + (c - v) * 0.5f;
    const bool s = (v - 1.0f) >= 0.0f;
    out[(size_t)t * BD + idx] = s ? 1.0f : 0.0f;
    v = s ? 0.0f : v;
  }
  vstate[idx] = v;
}

__global__ __launch_bounds__(64) void lif_bwd_kernel(
    const float* __restrict__ Y, float* __restrict__ out,
    int tlen, float* __restrict__ vstate, int carry)
{
#pragma clang fp contract(off)
  const int idx = blockIdx.x * 64 + threadIdx.x;
  float v = carry ? vstate[idx] : 0.0f;
#pragma unroll 16
  for (int tt = 0; tt < tlen; ++tt) {
    const size_t t = (size_t)(tlen - 1 - tt);
    const float c = Y[t * BD + idx];
    v = v + (c - v) * 0.5f;
    const bool s = (v - 1.0f) >= 0.0f;
    out[t * BD + idx] += s ? 1.0f : 0.0f;
    v = s ? 0.0f : v;
  }
  vstate[idx] = v;
}

// ---------------------------------------------------------------------------
extern "C" void kernel_launch(void* const* d_in, const int* in_sizes, int n_in,
                              void* d_out, int out_size, void* d_ws, size_t ws_size,
                              hipStream_t stream)
{
  const float* x = (const float*)d_in[0];   // [T, B, D]
  const float* W = (const float*)d_in[1];   // [D, D]
  const float* b = (const float*)d_in[2];   // [D]
  float* out = (float*)d_out;               // [T, B, D]

  const size_t full_bytes = (size_t)T_LEN * BD * sizeof(float);     // 134 MB
  const size_t bit_bytes  = (size_t)(T_LEN / 32) * BD * sizeof(uint32_t); // 4 MB
  const size_t vbytes     = (size_t)BD * sizeof(float);

  if (ws_size >= full_bytes + 2 * bit_bytes) {
    float*    Y  = (float*)d_ws;
    uint32_t* bf = (uint32_t*)((char*)d_ws + full_bytes);
    uint32_t* bb = (uint32_t*)((char*)d_ws + full_bytes + bit_bytes);
    dim3 grid(T_LEN * B_SZ / BM, D_SZ / BN);
    gemm8x8_kernel<<<grid, 256, 0, stream>>>(x, W, b, Y);
    scan_dirs_kernel<<<512, 64, 0, stream>>>(Y, bf, bb);
    combine_kernel<<<(T_LEN * BD / 4) / 256, 256, 0, stream>>>(bf, bb, out);
  } else if (ws_size >= full_bytes + vbytes) {
    float* Y      = (float*)d_ws;
    float* vstate = (float*)((char*)d_ws + full_bytes);
    dim3 grid(T_LEN * B_SZ / BM, D_SZ / BN);
    gemm8x8_kernel<<<grid, 256, 0, stream>>>(x, W, b, Y);
    lif_fwd_kernel<<<BD / 64, 64, 0, stream>>>(Y, out, T_LEN, vstate, 0);
    lif_bwd_kernel<<<BD / 64, 64, 0, stream>>>(Y, out, T_LEN, vstate, 0);
  } else {
    // Chunked fallback; Tc a power-of-two divisor of T_LEN (>=4) so chunk
    // rows are a multiple of BM=128.
    const size_t avail = ws_size > vbytes ? ws_size - vbytes : 0;
    int Tc = T_LEN;
    while (Tc > 4 && (size_t)Tc * BD * sizeof(float) > avail) Tc >>= 1;
    float* Y      = (float*)d_ws;
    float* vstate = (float*)((char*)d_ws + (size_t)Tc * BD * sizeof(float));

    int first = 1;
    for (int t0 = 0; t0 < T_LEN; t0 += Tc) {
      dim3 grid(Tc * B_SZ / BM, D_SZ / BN);
      gemm8x8_kernel<<<grid, 256, 0, stream>>>(x + (size_t)t0 * BD, W, b, Y);
      lif_fwd_kernel<<<BD / 64, 64, 0, stream>>>(Y, out + (size_t)t0 * BD, Tc,
                                                 vstate, first ? 0 : 1);
      first = 0;
    }
    first = 1;
    for (int t0 = T_LEN - Tc; t0 >= 0; t0 -= Tc) {
      dim3 grid(Tc * B_SZ / BM, D_SZ / BN);
      gemm8x8_kernel<<<grid, 256, 0, stream>>>(x + (size_t)t0 * BD, W, b, Y);
      lif_bwd_kernel<<<BD / 64, 64, 0, stream>>>(Y, out + (size_t)t0 * BD, Tc,
                                                 vstate, first ? 0 : 1);
      first = 0;
    }
  }
}